// Round 1
// baseline (272.470 us; speedup 1.0000x reference)
//
#include <hip/hip_runtime.h>
#include <math.h>

#define BB 4
#define NN 512
#define DD 64
#define EPS 1e-5f
#define NEG_SLOPE 0.01f

// Kernel A: per-row LayerNorm folded into the two projections.
// One wave (64 lanes) per row; lane d holds i_em[row, d].
__global__ void __launch_bounds__(256)
stats_kernel(const float* __restrict__ i_em,
             const float* __restrict__ W_a,
             const float* __restrict__ gamma,
             const float* __restrict__ beta,
             float* __restrict__ sq,
             float* __restrict__ sk) {
    int row  = (blockIdx.x * blockDim.x + threadIdx.x) >> 6;   // global wave id
    int lane = threadIdx.x & 63;
    if (row >= BB * NN) return;

    float x = i_em[row * DD + lane];

    float s = x;
    #pragma unroll
    for (int off = 32; off >= 1; off >>= 1) s += __shfl_xor(s, off, 64);
    float mu = s * (1.0f / DD);

    float dx = x - mu;
    float v = dx * dx;
    #pragma unroll
    for (int off = 32; off >= 1; off >>= 1) v += __shfl_xor(v, off, 64);
    float rstd = rsqrtf(v * (1.0f / DD) + EPS);

    float xn = dx * rstd * gamma[lane] + beta[lane];
    float pq = xn * W_a[lane];
    float pk = xn * W_a[DD + lane];
    #pragma unroll
    for (int off = 32; off >= 1; off >>= 1) {
        pq += __shfl_xor(pq, off, 64);
        pk += __shfl_xor(pk, off, 64);
    }
    if (lane == 0) { sq[row] = pq; sk[row] = pk; }
}

// Kernel B: one block per (b, i).
// Phase 1: softmax over j of leaky(sq[i] + sk[j] + bias) -> alphas[b,i,:].
// Phase 2: value[b,i,j,:] = i_em[b,i,:] * i_em[b,j,:] via float4 stores.
__global__ void __launch_bounds__(256)
attn_kernel(const float* __restrict__ i_em,
            const float* __restrict__ sq,
            const float* __restrict__ sk,
            const float* __restrict__ b_a,
            float* __restrict__ alphas,
            float* __restrict__ value) {
    __shared__ float red[4];

    const int blk = blockIdx.x;      // b*NN + i
    const int b   = blk >> 9;        // / NN
    const int t   = threadIdx.x;

    const float bias = b_a[0];
    const float si   = sq[blk];

    // --- scores for j = t and j = t+256 ---
    float s0 = si + sk[b * NN + t]       + bias;
    s0 = (s0 >= 0.f) ? s0 : NEG_SLOPE * s0;
    float s1 = si + sk[b * NN + t + 256] + bias;
    s1 = (s1 >= 0.f) ? s1 : NEG_SLOPE * s1;

    // --- block max ---
    float m = fmaxf(s0, s1);
    #pragma unroll
    for (int off = 32; off >= 1; off >>= 1) m = fmaxf(m, __shfl_xor(m, off, 64));
    const int w = t >> 6;
    if ((t & 63) == 0) red[w] = m;
    __syncthreads();
    m = fmaxf(fmaxf(red[0], red[1]), fmaxf(red[2], red[3]));
    __syncthreads();

    // --- exp + block sum ---
    float e0 = expf(s0 - m);
    float e1 = expf(s1 - m);
    float sum = e0 + e1;
    #pragma unroll
    for (int off = 32; off >= 1; off >>= 1) sum += __shfl_xor(sum, off, 64);
    if ((t & 63) == 0) red[w] = sum;
    __syncthreads();
    sum = red[0] + red[1] + red[2] + red[3];
    const float inv = 1.0f / sum;

    alphas[blk * NN + t]       = e0 * inv;
    alphas[blk * NN + t + 256] = e1 * inv;

    // --- phase 2: outer-product value writes ---
    const float4* em4 = (const float4*)i_em;
    const int d4 = t & 15;          // which float4 of D=64
    const int jg = t >> 4;          // j group 0..15
    const float4 xi = em4[blk * 16 + d4];
    const float4* emb = em4 + (size_t)b * NN * 16;
    float4* out4 = (float4*)value + (size_t)blk * (NN * 16);

    #pragma unroll 4
    for (int j = jg; j < NN; j += 16) {
        float4 xj = emb[j * 16 + d4];
        float4 o;
        o.x = xi.x * xj.x;
        o.y = xi.y * xj.y;
        o.z = xi.z * xj.z;
        o.w = xi.w * xj.w;
        out4[j * 16 + d4] = o;      // lanes 0..63 of each wave -> 1 KB contiguous
    }
}

extern "C" void kernel_launch(void* const* d_in, const int* in_sizes, int n_in,
                              void* d_out, int out_size, void* d_ws, size_t ws_size,
                              hipStream_t stream) {
    const float* i_em  = (const float*)d_in[0];
    const float* W_a   = (const float*)d_in[1];
    const float* b_a   = (const float*)d_in[2];
    const float* gamma = (const float*)d_in[3];
    const float* beta  = (const float*)d_in[4];

    float* alphas = (float*)d_out;                       // B*N*N
    float* value  = (float*)d_out + (size_t)BB * NN * NN; // B*N*N*D

    float* sq = (float*)d_ws;          // B*N
    float* sk = sq + BB * NN;          // B*N

    // 2048 rows, 4 waves per 256-thread block -> 512 blocks
    stats_kernel<<<(BB * NN) / 4, 256, 0, stream>>>(i_em, W_a, gamma, beta, sq, sk);
    // one block per (b, i)
    attn_kernel<<<BB * NN, 256, 0, stream>>>(i_em, sq, sk, b_a, alphas, value);
}